// Round 6
// baseline (343.413 us; speedup 1.0000x reference)
//
#include <hip/hip_runtime.h>

// QRNN3D fused: conv3d(16->48,3x3x3,SAME) + gates + fo-pool via bf16 MFMA.
// Round 9 = round 8 + amdgpu_waves_per_eu(2,2). Round 8's weights-in-reg
// never ran as designed: launch_bounds(256,2) only sets MIN waves/EU, and
// the allocator targeted 4 waves/EU (VGPR_Count=128), spilling the 112
// weight VGPRs to scratch (WRITE +32MB, FETCH +16MB, 135->188us). Pinning
// min=max=2 waves/EU raises the cap to 256 VGPR -> ~210 live fits, no
// spill. Occupancy is unchanged anyway: LDS (40448B -> 2 blocks in 160K at
// 4 waves each... grid=512=2xCU) already caps residency at 8 waves/CU.
//
// Round 7/8 change (from 135us/dispatch, LDS pipe 44% = top resource, 59%
// of LDS traffic = per-t weight re-reads):
//  - g=0,1 weight A-frags (28 frags = 112 VGPR) live in REGISTERS, loaded
//    once from global (L2/L3-resident). g=2 stays in LDS (14336B). Weight
//    LDS traffic per block-t: 172KB -> 57KB; total LDS 293 -> 178KB.
//  - lds_write at TOP of body: with NSLOT=4, slot r3's last reader was
//    iteration t-1 (barrier-protected), so the plane-(t+2) write may
//    precede the MFMA block and drain in its shadow. rv is a SINGLE buffer
//    with one-full-iteration load depth.
//  - LDS static 40448B (<64K); one barrier per t.
//
// GEMM: gates[48][px] = W[48][K=448] * im2col[K][px]; K = tap*16+ic,
// tap = kd*9+kh*3+kw (27 real, pad tap 27 has W==0).
// mfma_f32_16x16x32_bf16: A[m][k=q*8+j] = W, B[k][n=px], C/D col=lane&15,
// row=q*4+reg. Wave owns 32 px x 16 hidden ch; z/f/o accs lane-aligned so
// the t-recurrence is per-lane register math.

typedef __attribute__((ext_vector_type(8))) short short8;
typedef __attribute__((ext_vector_type(4))) float float4v;

#define TD 31
#define HW (128 * 128)
#define LH 6                         // 4 tile rows + 2 halo
#define LW 34                        // 32 tile cols + 2 halo
#define UNITS (LH * 2 * LW)          // 408 short8 units per plane
#define NSLOT 4
#define SLOTB (UNITS * 16)           // 6528 B per ring slot
#define W2UNITS (14 * 64)            // g=2 weight units (14336 B)

__device__ __forceinline__ short f2bf(float f) {
    unsigned u = __float_as_uint(f);
    u = (u + 0x7FFFu + ((u >> 16) & 1u)) >> 16;   // RNE
    return (short)u;
}

__device__ __forceinline__ float frcp(float x) { return __builtin_amdgcn_rcpf(x); }

__device__ __forceinline__ unsigned cvtpk(float lo, float hi) {
    unsigned r;
    asm("v_cvt_pk_bf16_f32 %0, %1, %2" : "=v"(r) : "v"(lo), "v"(hi));
    return r;
}

// Barrier WITHOUT the compiler's vmcnt(0) drain. lgkmcnt(0) orders LDS;
// global loads target private registers (compiler-tracked vmcnt at use).
#define BARRIER() asm volatile("s_waitcnt lgkmcnt(0)\n\ts_barrier" ::: "memory")

__global__ __launch_bounds__(256)
__attribute__((amdgpu_waves_per_eu(2, 2)))
void qrnn_mfma6(
    const float* __restrict__ x,     // (4,16,31,128,128)
    const float* __restrict__ wt,    // (48,16,27)
    const float* __restrict__ bias,  // (48)
    float* __restrict__ out)         // (4,16,31,128,128)
{
    __shared__ short8 wlds2[W2UNITS];        // 14336 B (g=2 A-frags)
    __shared__ short8 ring[NSLOT * UNITS];   // 26112 B  -> total 40448 B

    const int tid  = threadIdx.x;
    const int lane = tid & 63;
    const int wv   = tid >> 6;       // wave id = h row in tile
    const int q    = lane >> 4;
    const int px   = lane & 15;
    const int b    = blockIdx.x;     // 512 blocks
    const int n    = b >> 7;
    const int h0   = ((b >> 2) & 31) * 4;
    const int w0   = (b & 3) * 32;

    const float* xin = x + (size_t)n * (16 * TD * HW);

    // ---- g=0,1 weight A-frags -> registers (28 frags, 112 VGPR).
    //      A-frag row m = lane&15 = px; k = q*8+j within the s-step. ----
    short8 wreg[2][14];
#pragma unroll
    for (int g = 0; g < 2; ++g)
#pragma unroll
        for (int s = 0; s < 14; ++s) {
            short8 a;
#pragma unroll
            for (int j = 0; j < 8; ++j) {
                int kk = s * 32 + q * 8 + j;
                int tap = kk >> 4, ic = kk & 15;
                float v = (tap < 27) ? wt[((size_t)((g * 16 + px) * 16 + ic)) * 27 + tap] : 0.f;
                a[j] = f2bf(v);
            }
            wreg[g][s] = a;
        }

    // ---- g=2 weight A-frags -> LDS: wlds2[s*64 + lane] ----
    for (int k = 0; k < 4; ++k) {
        int u = tid + k * 256;
        if (u < W2UNITS) {
            int l = u & 63, s = u >> 6;
            int qq = l >> 4, m = l & 15;
            short8 a;
#pragma unroll
            for (int j = 0; j < 8; ++j) {
                int kk = s * 32 + qq * 8 + j;
                int tap = kk >> 4, ic = kk & 15;
                float v = (tap < 27) ? wt[((size_t)((32 + m) * 16 + ic)) * 27 + tap] : 0.f;
                a[j] = f2bf(v);
            }
            wlds2[u] = a;
        }
    }
    // ---- zero all ring slots once (halo-invalid units stay 0 forever;
    //      plane -1 = slot 3 stays 0) ----
    {
        short8 z = (short8)0;
        for (int k = 0; k < 7; ++k) {
            int u = tid + k * 256;
            if (u < NSLOT * UNITS) ring[u] = z;
        }
    }

    // ---- staging: 1 VGPR voffset per unit + 8 uniform SGPR plane bases ----
    unsigned voff[2];
    bool s_ok[2];
#pragma unroll
    for (int i = 0; i < 2; ++i) {
        int u    = tid + i * 256;
        int uu   = (u < UNITS) ? u : 0;
        int wp   = uu % LW;
        int rest = uu / LW;
        int ck   = rest & 1;
        int hp   = rest >> 1;
        int hh   = h0 + hp - 1;
        int ww   = w0 + wp - 1;
        s_ok[i] = (u < UNITS) && ((unsigned)hh < 128u) && ((unsigned)ww < 128u);
        int hc = hh < 0 ? 0 : (hh > 127 ? 127 : hh);   // clamped safe coords
        int wc = ww < 0 ? 0 : (ww > 127 ? 127 : ww);
        voff[i] = (unsigned)(ck * (8 * TD * HW) + hc * 128 + wc);
    }

    float rv[2][8];                  // single staging buffer

    // loads ALWAYS issued at safe clamped addresses; saddr-form:
    // uniform base (xin + tc*HW + j*TD*HW) + per-lane 32-bit voffset.
    auto issue = [&](int tt) {
        const int tc = ((unsigned)tt >= 31u) ? 0 : tt;
        const float* basep = xin + (size_t)tc * HW;
#pragma unroll
        for (int j = 0; j < 8; ++j) {
            const float* bj = basep + (size_t)j * (TD * HW);   // uniform
            rv[0][j] = bj[voff[0]];
            rv[1][j] = bj[voff[1]];
        }
    };

    // tz is wave-uniform: zero-write path is a uniform branch (t>=29 only).
    auto lds_write = [&](int wu, bool tz) {
        if (!tz) {
#pragma unroll
            for (int i = 0; i < 2; ++i) {
                if (s_ok[i]) {
                    union { short8 s; unsigned u[4]; } v;
#pragma unroll
                    for (int k = 0; k < 4; ++k)
                        v.u[k] = cvtpk(rv[i][2 * k], rv[i][2 * k + 1]);
                    ring[wu + tid + i * 256] = v.s;
                }
            }
        } else {
            short8 z = (short8)0;
#pragma unroll
            for (int i = 0; i < 2; ++i)
                if (s_ok[i]) ring[wu + tid + i * 256] = z;
        }
    };

    // ---- ring tap offsets (t-invariant). kd compile-time except s=4. ----
    int roff[14];
#pragma unroll
    for (int s = 0; s < 14; ++s) {
        int T = 2 * s + (q >> 1); if (T > 26) T = 26;
        int kd = T / 9, rr = T - kd * 9, kh = rr / 3, kw = rr - kh * 3;
        roff[s] = (((wv + kh) * 2 + (q & 1)) * LW + px + kw) * 16;  // bytes
    }
    const int kd4 = q >> 1;          // kd for s==4: taps 8 (kd=0) / 9 (kd=1)

    // bias per lane: channel = g*16 + q*4 + r
    float4v bv[3];
#pragma unroll
    for (int g = 0; g < 3; ++g)
        bv[g] = (float4v){bias[g * 16 + q * 4 + 0], bias[g * 16 + q * 4 + 1],
                          bias[g * 16 + q * 4 + 2], bias[g * 16 + q * 4 + 3]};

    float* po = out + ((size_t)(n * 16 + q * 4) * TD) * HW
                    + (size_t)(h0 + wv) * 128 + w0 + px;
    float cst[2][4] = {{0.f,0.f,0.f,0.f},{0.f,0.f,0.f,0.f}};

    // ---- prologue. slot(p) = p&3; plane -1 -> slot 3 (zeros).
    //      Ring slots are 408 units (NOT 256-aligned): the zero-fill of a
    //      unit and its plane-write can come from different threads ->
    //      barrier between them is REQUIRED. ----
    BARRIER();
    issue(0); lds_write(0 * UNITS, false);
    issue(1); lds_write(1 * UNITS, false);
    issue(2);                        // rv = plane 2, written by body(0)
    BARRIER();

    // body(t): slots r0..r3 hold planes t-1..t+2. Write plane t+2 (from rv,
    // issued at t-1) into r3 FIRST — r3's last reader was t-1 (barriered) —
    // then refill rv with plane t+3; MFMA block reads r0..r2 meanwhile.
    int r0 = 3 * SLOTB, r1 = 0, r2 = SLOTB, r3 = 2 * SLOTB;
    for (int t = 0; t < TD; ++t) {
        lds_write(r3 >> 4, t >= 29);     // plane t+2 (zeros for t>=29)
        issue(t + 3);                    // in flight until body(t+1)

        float4v acc[2][3];
#pragma unroll
        for (int g = 0; g < 3; ++g) { acc[0][g] = bv[g]; acc[1][g] = bv[g]; }

        const int pk[3] = {r0, r1, r2};
        constexpr int kdt[14] = {0,0,0,0, 0 /*s=4 special*/, 1,1,1,1, 2,2,2,2,2};
        const char* ringb = (const char*)ring;
#pragma unroll
        for (int s = 0; s < 14; ++s) {
            int sb = (s == 4) ? (kd4 ? r1 : r0) : pk[kdt[s]];
            const short8* bp = (const short8*)(ringb + sb + roff[s]);
            short8 wf2 = wlds2[s * 64 + lane];   // g=2 frag (LDS)
            short8 b0 = bp[0];           // ds_read_b128, conflict-free
            short8 b1 = bp[16];          // +16 w cols, offset:256 immediate
            acc[0][0] = __builtin_amdgcn_mfma_f32_16x16x32_bf16(wreg[0][s], b0, acc[0][0], 0, 0, 0);
            acc[1][0] = __builtin_amdgcn_mfma_f32_16x16x32_bf16(wreg[0][s], b1, acc[1][0], 0, 0, 0);
            acc[0][1] = __builtin_amdgcn_mfma_f32_16x16x32_bf16(wreg[1][s], b0, acc[0][1], 0, 0, 0);
            acc[1][1] = __builtin_amdgcn_mfma_f32_16x16x32_bf16(wreg[1][s], b1, acc[1][1], 0, 0, 0);
            acc[0][2] = __builtin_amdgcn_mfma_f32_16x16x32_bf16(wf2, b0, acc[0][2], 0, 0, 0);
            acc[1][2] = __builtin_amdgcn_mfma_f32_16x16x32_bf16(wf2, b1, acc[1][2], 0, 0, 0);
        }

        // activations + fo-pool + store (rcp fast path)
#pragma unroll
        for (int tile = 0; tile < 2; ++tile) {
#pragma unroll
            for (int r = 0; r < 4; ++r) {
                float az = acc[tile][0][r];
                float af = acc[tile][1][r];
                float ao = acc[tile][2][r];
                float z = 1.f - 2.f * frcp(__expf(2.f * az) + 1.f);
                float f = frcp(1.f + __expf(-af));
                float o = frcp(1.f + __expf(-ao));
                float c = f * cst[tile][r] + (1.f - f) * z;
                cst[tile][r] = c;
                po[(size_t)r * (TD * HW) + tile * 16] = o * c;
            }
        }
        po += HW;
        BARRIER();   // my reads of r0..r2 done (lgkmcnt 0) + write of r3
                     // visible -> next iter may read r3's plane & reuse r0
        int tmp = r0; r0 = r1; r1 = r2; r2 = r3; r3 = tmp;
    }
}

extern "C" void kernel_launch(void* const* d_in, const int* in_sizes, int n_in,
                              void* d_out, int out_size, void* d_ws, size_t ws_size,
                              hipStream_t stream) {
    const float* x    = (const float*)d_in[0];
    const float* wt   = (const float*)d_in[1];
    const float* bias = (const float*)d_in[2];
    float* out = (float*)d_out;

    // grid: n(4) x hblk(32) x wblk(4) = 512 blocks of 256 threads (4 waves)
    qrnn_mfma6<<<dim3(512), dim3(256), 0, stream>>>(x, wt, bias, out);
}

// Round 7
// 332.935 us; speedup vs baseline: 1.0315x; 1.0315x over previous
//
#include <hip/hip_runtime.h>

// QRNN3D fused: conv3d(16->48,3x3x3,SAME) + gates + fo-pool via bf16 MFMA.
// Round 10 = round 8/9 kernel with __launch_bounds__(256, 1).
// History of the weights-in-registers experiment:
//   r8: launch_bounds(256,2)            -> VGPR capped 128, 112 wregs spill,
//                                          WRITE +32MB scratch, 188us.
//   r9: launch_bounds(256)+waves_per_eu(2,2) -> identical: 128 VGPR, spill.
//   r10: launch_bounds(256, 1) — the documented knob (min waves/EU = 1)
//        lifts the allocator budget toward 512. Live set ~210. Occupancy
//        CANNOT regress: grid = 2 blocks/CU and any VGPR in 129..256 still
//        allows 2 waves/SIMD = 8 waves/CU = this grid's full residency.
//
// Round 7/8 design (from 135us/dispatch, LDS pipe 44% = top resource, 59%
// of LDS traffic = per-t weight re-reads):
//  - g=0,1 weight A-frags (28 frags = 112 VGPR) live in REGISTERS, loaded
//    once from global (L2/L3-resident). g=2 stays in LDS (14336B). Weight
//    LDS traffic per block-t: 172KB -> 57KB; total LDS 293 -> 178KB.
//  - lds_write at TOP of body: with NSLOT=4, slot r3's last reader was
//    iteration t-1 (barrier-protected), so the plane-(t+2) write may
//    precede the MFMA block and drain in its shadow. rv is a SINGLE buffer
//    with one-full-iteration load depth.
//  - LDS static 40448B (<64K); one barrier per t.
//
// GEMM: gates[48][px] = W[48][K=448] * im2col[K][px]; K = tap*16+ic,
// tap = kd*9+kh*3+kw (27 real, pad tap 27 has W==0).
// mfma_f32_16x16x32_bf16: A[m][k=q*8+j] = W, B[k][n=px], C/D col=lane&15,
// row=q*4+reg. Wave owns 32 px x 16 hidden ch; z/f/o accs lane-aligned so
// the t-recurrence is per-lane register math.

typedef __attribute__((ext_vector_type(8))) short short8;
typedef __attribute__((ext_vector_type(4))) float float4v;

#define TD 31
#define HW (128 * 128)
#define LH 6                         // 4 tile rows + 2 halo
#define LW 34                        // 32 tile cols + 2 halo
#define UNITS (LH * 2 * LW)          // 408 short8 units per plane
#define NSLOT 4
#define SLOTB (UNITS * 16)           // 6528 B per ring slot
#define W2UNITS (14 * 64)            // g=2 weight units (14336 B)

__device__ __forceinline__ short f2bf(float f) {
    unsigned u = __float_as_uint(f);
    u = (u + 0x7FFFu + ((u >> 16) & 1u)) >> 16;   // RNE
    return (short)u;
}

__device__ __forceinline__ float frcp(float x) { return __builtin_amdgcn_rcpf(x); }

__device__ __forceinline__ unsigned cvtpk(float lo, float hi) {
    unsigned r;
    asm("v_cvt_pk_bf16_f32 %0, %1, %2" : "=v"(r) : "v"(lo), "v"(hi));
    return r;
}

// Barrier WITHOUT the compiler's vmcnt(0) drain. lgkmcnt(0) orders LDS;
// global loads target private registers (compiler-tracked vmcnt at use).
#define BARRIER() asm volatile("s_waitcnt lgkmcnt(0)\n\ts_barrier" ::: "memory")

__global__ __launch_bounds__(256, 1) void qrnn_mfma7(
    const float* __restrict__ x,     // (4,16,31,128,128)
    const float* __restrict__ wt,    // (48,16,27)
    const float* __restrict__ bias,  // (48)
    float* __restrict__ out)         // (4,16,31,128,128)
{
    __shared__ short8 wlds2[W2UNITS];        // 14336 B (g=2 A-frags)
    __shared__ short8 ring[NSLOT * UNITS];   // 26112 B  -> total 40448 B

    const int tid  = threadIdx.x;
    const int lane = tid & 63;
    const int wv   = tid >> 6;       // wave id = h row in tile
    const int q    = lane >> 4;
    const int px   = lane & 15;
    const int b    = blockIdx.x;     // 512 blocks
    const int n    = b >> 7;
    const int h0   = ((b >> 2) & 31) * 4;
    const int w0   = (b & 3) * 32;

    const float* xin = x + (size_t)n * (16 * TD * HW);

    // ---- g=0,1 weight A-frags -> registers (28 frags, 112 VGPR).
    //      A-frag row m = lane&15 = px; k = q*8+j within the s-step. ----
    short8 wreg[2][14];
#pragma unroll
    for (int g = 0; g < 2; ++g)
#pragma unroll
        for (int s = 0; s < 14; ++s) {
            short8 a;
#pragma unroll
            for (int j = 0; j < 8; ++j) {
                int kk = s * 32 + q * 8 + j;
                int tap = kk >> 4, ic = kk & 15;
                float v = (tap < 27) ? wt[((size_t)((g * 16 + px) * 16 + ic)) * 27 + tap] : 0.f;
                a[j] = f2bf(v);
            }
            wreg[g][s] = a;
        }

    // ---- g=2 weight A-frags -> LDS: wlds2[s*64 + lane] ----
    for (int k = 0; k < 4; ++k) {
        int u = tid + k * 256;
        if (u < W2UNITS) {
            int l = u & 63, s = u >> 6;
            int qq = l >> 4, m = l & 15;
            short8 a;
#pragma unroll
            for (int j = 0; j < 8; ++j) {
                int kk = s * 32 + qq * 8 + j;
                int tap = kk >> 4, ic = kk & 15;
                float v = (tap < 27) ? wt[((size_t)((32 + m) * 16 + ic)) * 27 + tap] : 0.f;
                a[j] = f2bf(v);
            }
            wlds2[u] = a;
        }
    }
    // ---- zero all ring slots once (halo-invalid units stay 0 forever;
    //      plane -1 = slot 3 stays 0) ----
    {
        short8 z = (short8)0;
        for (int k = 0; k < 7; ++k) {
            int u = tid + k * 256;
            if (u < NSLOT * UNITS) ring[u] = z;
        }
    }

    // ---- staging: 1 VGPR voffset per unit + 8 uniform SGPR plane bases ----
    unsigned voff[2];
    bool s_ok[2];
#pragma unroll
    for (int i = 0; i < 2; ++i) {
        int u    = tid + i * 256;
        int uu   = (u < UNITS) ? u : 0;
        int wp   = uu % LW;
        int rest = uu / LW;
        int ck   = rest & 1;
        int hp   = rest >> 1;
        int hh   = h0 + hp - 1;
        int ww   = w0 + wp - 1;
        s_ok[i] = (u < UNITS) && ((unsigned)hh < 128u) && ((unsigned)ww < 128u);
        int hc = hh < 0 ? 0 : (hh > 127 ? 127 : hh);   // clamped safe coords
        int wc = ww < 0 ? 0 : (ww > 127 ? 127 : ww);
        voff[i] = (unsigned)(ck * (8 * TD * HW) + hc * 128 + wc);
    }

    float rv[2][8];                  // single staging buffer

    // loads ALWAYS issued at safe clamped addresses; saddr-form:
    // uniform base (xin + tc*HW + j*TD*HW) + per-lane 32-bit voffset.
    auto issue = [&](int tt) {
        const int tc = ((unsigned)tt >= 31u) ? 0 : tt;
        const float* basep = xin + (size_t)tc * HW;
#pragma unroll
        for (int j = 0; j < 8; ++j) {
            const float* bj = basep + (size_t)j * (TD * HW);   // uniform
            rv[0][j] = bj[voff[0]];
            rv[1][j] = bj[voff[1]];
        }
    };

    // tz is wave-uniform: zero-write path is a uniform branch (t>=29 only).
    auto lds_write = [&](int wu, bool tz) {
        if (!tz) {
#pragma unroll
            for (int i = 0; i < 2; ++i) {
                if (s_ok[i]) {
                    union { short8 s; unsigned u[4]; } v;
#pragma unroll
                    for (int k = 0; k < 4; ++k)
                        v.u[k] = cvtpk(rv[i][2 * k], rv[i][2 * k + 1]);
                    ring[wu + tid + i * 256] = v.s;
                }
            }
        } else {
            short8 z = (short8)0;
#pragma unroll
            for (int i = 0; i < 2; ++i)
                if (s_ok[i]) ring[wu + tid + i * 256] = z;
        }
    };

    // ---- ring tap offsets (t-invariant). kd compile-time except s=4. ----
    int roff[14];
#pragma unroll
    for (int s = 0; s < 14; ++s) {
        int T = 2 * s + (q >> 1); if (T > 26) T = 26;
        int kd = T / 9, rr = T - kd * 9, kh = rr / 3, kw = rr - kh * 3;
        roff[s] = (((wv + kh) * 2 + (q & 1)) * LW + px + kw) * 16;  // bytes
    }
    const int kd4 = q >> 1;          // kd for s==4: taps 8 (kd=0) / 9 (kd=1)

    // bias per lane: channel = g*16 + q*4 + r
    float4v bv[3];
#pragma unroll
    for (int g = 0; g < 3; ++g)
        bv[g] = (float4v){bias[g * 16 + q * 4 + 0], bias[g * 16 + q * 4 + 1],
                          bias[g * 16 + q * 4 + 2], bias[g * 16 + q * 4 + 3]};

    float* po = out + ((size_t)(n * 16 + q * 4) * TD) * HW
                    + (size_t)(h0 + wv) * 128 + w0 + px;
    float cst[2][4] = {{0.f,0.f,0.f,0.f},{0.f,0.f,0.f,0.f}};

    // ---- prologue. slot(p) = p&3; plane -1 -> slot 3 (zeros).
    //      Ring slots are 408 units (NOT 256-aligned): the zero-fill of a
    //      unit and its plane-write can come from different threads ->
    //      barrier between them is REQUIRED. ----
    BARRIER();
    issue(0); lds_write(0 * UNITS, false);
    issue(1); lds_write(1 * UNITS, false);
    issue(2);                        // rv = plane 2, written by body(0)
    BARRIER();

    // body(t): slots r0..r3 hold planes t-1..t+2. Write plane t+2 (from rv,
    // issued at t-1) into r3 FIRST — r3's last reader was t-1 (barriered) —
    // then refill rv with plane t+3; MFMA block reads r0..r2 meanwhile.
    int r0 = 3 * SLOTB, r1 = 0, r2 = SLOTB, r3 = 2 * SLOTB;
    for (int t = 0; t < TD; ++t) {
        lds_write(r3 >> 4, t >= 29);     // plane t+2 (zeros for t>=29)
        issue(t + 3);                    // in flight until body(t+1)

        float4v acc[2][3];
#pragma unroll
        for (int g = 0; g < 3; ++g) { acc[0][g] = bv[g]; acc[1][g] = bv[g]; }

        const int pk[3] = {r0, r1, r2};
        constexpr int kdt[14] = {0,0,0,0, 0 /*s=4 special*/, 1,1,1,1, 2,2,2,2,2};
        const char* ringb = (const char*)ring;
#pragma unroll
        for (int s = 0; s < 14; ++s) {
            int sb = (s == 4) ? (kd4 ? r1 : r0) : pk[kdt[s]];
            const short8* bp = (const short8*)(ringb + sb + roff[s]);
            short8 wf2 = wlds2[s * 64 + lane];   // g=2 frag (LDS)
            short8 b0 = bp[0];           // ds_read_b128, conflict-free
            short8 b1 = bp[16];          // +16 w cols, offset:256 immediate
            acc[0][0] = __builtin_amdgcn_mfma_f32_16x16x32_bf16(wreg[0][s], b0, acc[0][0], 0, 0, 0);
            acc[1][0] = __builtin_amdgcn_mfma_f32_16x16x32_bf16(wreg[0][s], b1, acc[1][0], 0, 0, 0);
            acc[0][1] = __builtin_amdgcn_mfma_f32_16x16x32_bf16(wreg[1][s], b0, acc[0][1], 0, 0, 0);
            acc[1][1] = __builtin_amdgcn_mfma_f32_16x16x32_bf16(wreg[1][s], b1, acc[1][1], 0, 0, 0);
            acc[0][2] = __builtin_amdgcn_mfma_f32_16x16x32_bf16(wf2, b0, acc[0][2], 0, 0, 0);
            acc[1][2] = __builtin_amdgcn_mfma_f32_16x16x32_bf16(wf2, b1, acc[1][2], 0, 0, 0);
        }

        // activations + fo-pool + store (rcp fast path)
#pragma unroll
        for (int tile = 0; tile < 2; ++tile) {
#pragma unroll
            for (int r = 0; r < 4; ++r) {
                float az = acc[tile][0][r];
                float af = acc[tile][1][r];
                float ao = acc[tile][2][r];
                float z = 1.f - 2.f * frcp(__expf(2.f * az) + 1.f);
                float f = frcp(1.f + __expf(-af));
                float o = frcp(1.f + __expf(-ao));
                float c = f * cst[tile][r] + (1.f - f) * z;
                cst[tile][r] = c;
                po[(size_t)r * (TD * HW) + tile * 16] = o * c;
            }
        }
        po += HW;
        BARRIER();   // my reads of r0..r2 done (lgkmcnt 0) + write of r3
                     // visible -> next iter may read r3's plane & reuse r0
        int tmp = r0; r0 = r1; r1 = r2; r2 = r3; r3 = tmp;
    }
}

extern "C" void kernel_launch(void* const* d_in, const int* in_sizes, int n_in,
                              void* d_out, int out_size, void* d_ws, size_t ws_size,
                              hipStream_t stream) {
    const float* x    = (const float*)d_in[0];
    const float* wt   = (const float*)d_in[1];
    const float* bias = (const float*)d_in[2];
    float* out = (float*)d_out;

    // grid: n(4) x hblk(32) x wblk(4) = 512 blocks of 256 threads (4 waves)
    qrnn_mfma7<<<dim3(512), dim3(256), 0, stream>>>(x, wt, bias, out);
}

// Round 8
// 300.519 us; speedup vs baseline: 1.1427x; 1.1079x over previous
//
#include <hip/hip_runtime.h>

// QRNN3D fused: conv3d(16->48,3x3x3,SAME) + gates + fo-pool via bf16 MFMA.
// Round 11: 2-timestep-unrolled body with weight-read amortization.
// r8/r9/r10 proved weights-in-VGPR can't coexist with 2 blocks/CU on this
// toolchain (allocator either caps 128+spills or balloons AGPR total >256
// -> 1 block/CU). Same goal achieved structurally: one weight-frag LDS read
// feeds the MFMAs of BOTH t and t+1 (weights are t-invariant).
//   per-wave ds_reads / 2t: 42 weight + 56 B = 98  (r6: 140)  -> LDS bytes
//   per CU-t 573KB -> 405KB, the binding resource per the r6 model.
// Ring stays NSLOT=4: iteration (t,t+1) reads planes t-1..t+2 (slots r0..r3),
// then after a mid-barrier writes planes t+3,t+4 over slots r0,r1; rotation
// is (r0..r3) <- (r2,r3,r0,r1). 2 barriers per 2t = same rate as r6.
// Registers: +24 acc (2nd t) +16 staging (2nd plane) over r6's 80; roff
// packed 2x16b into 7 regs. Target <=128 under the proven (256,2) cap.
// LDS 69120B dynamic; 2 blocks/CU = 138240 <= 163840.
//
// GEMM: gates[48][px] = W[48][K=448] * im2col[K][px]; K = tap*16+ic,
// tap = kd*9+kh*3+kw (27 real, pad tap 27 has W==0).
// mfma_f32_16x16x32_bf16: A[m][k=q*8+j] = W, B[k][n=px], C/D col=lane&15,
// row=q*4+reg. Wave owns 32 px x 16 hidden ch; z/f/o accs lane-aligned so
// the t-recurrence is per-lane register math.

typedef __attribute__((ext_vector_type(8))) short short8;
typedef __attribute__((ext_vector_type(4))) float float4v;

#define TD 31
#define HW (128 * 128)
#define LH 6                         // 4 tile rows + 2 halo
#define LW 34                        // 32 tile cols + 2 halo
#define UNITS (LH * 2 * LW)          // 408 short8 units per plane
#define NSLOT 4
#define SLOTB (UNITS * 16)           // 6528 B per ring slot
#define WUNITS (14 * 3 * 64)         // 2688 weight units (43008 B)
#define SMEM_BYTES ((WUNITS + NSLOT * UNITS) * 16)   // 69120

__device__ __forceinline__ short f2bf(float f) {
    unsigned u = __float_as_uint(f);
    u = (u + 0x7FFFu + ((u >> 16) & 1u)) >> 16;   // RNE
    return (short)u;
}

__device__ __forceinline__ float frcp(float x) { return __builtin_amdgcn_rcpf(x); }

__device__ __forceinline__ unsigned cvtpk(float lo, float hi) {
    unsigned r;
    asm("v_cvt_pk_bf16_f32 %0, %1, %2" : "=v"(r) : "v"(lo), "v"(hi));
    return r;
}

// Barrier WITHOUT the compiler's vmcnt(0) drain. lgkmcnt(0) orders LDS;
// global loads target private registers (compiler-tracked vmcnt at use).
#define BARRIER() asm volatile("s_waitcnt lgkmcnt(0)\n\ts_barrier" ::: "memory")

#define MFMA(A, B, C) __builtin_amdgcn_mfma_f32_16x16x32_bf16((A), (B), (C), 0, 0, 0)

__global__ __launch_bounds__(256, 2) void qrnn_mfma8(
    const float* __restrict__ x,     // (4,16,31,128,128)
    const float* __restrict__ wt,    // (48,16,27)
    const float* __restrict__ bias,  // (48)
    float* __restrict__ out)         // (4,16,31,128,128)
{
    extern __shared__ short8 smem[];
    short8* wlds = smem;             // [WUNITS]
    short8* ring = smem + WUNITS;    // [NSLOT*UNITS]

    const int tid  = threadIdx.x;
    const int lane = tid & 63;
    const int wv   = tid >> 6;       // wave id = h row in tile
    const int q    = lane >> 4;
    const int px   = lane & 15;
    const int b    = blockIdx.x;     // 512 blocks
    const int n    = b >> 7;
    const int h0   = ((b >> 2) & 31) * 4;
    const int w0   = (b & 3) * 32;

    const float* xin = x + (size_t)n * (16 * TD * HW);

    // ---- fill weight LDS once: wlds[(s*3+g)*64 + lane] = A-frag ----
    for (int k = 0; k < 11; ++k) {
        int u = tid + k * 256;
        if (u < WUNITS) {
            int l = u & 63, rest = u >> 6;
            int g = rest % 3, s = rest / 3;
            int qq = l >> 4, m = l & 15;
            short8 a;
#pragma unroll
            for (int j = 0; j < 8; ++j) {
                int kk = s * 32 + qq * 8 + j;
                int tap = kk >> 4, ic = kk & 15;
                float v = (tap < 27) ? wt[((size_t)((g * 16 + m) * 16 + ic)) * 27 + tap] : 0.f;
                a[j] = f2bf(v);
            }
            wlds[u] = a;
        }
    }
    // ---- zero all ring slots once (halo-invalid units stay 0 forever;
    //      plane -1 = slot 3 stays 0) ----
    {
        short8 z = (short8)0;
        for (int k = 0; k < 7; ++k) {
            int u = tid + k * 256;
            if (u < NSLOT * UNITS) ring[u] = z;
        }
    }

    // ---- staging: 1 VGPR voffset per unit + uniform SGPR plane bases ----
    unsigned voff[2];
    bool s_ok[2];
#pragma unroll
    for (int i = 0; i < 2; ++i) {
        int u    = tid + i * 256;
        int uu   = (u < UNITS) ? u : 0;
        int wp   = uu % LW;
        int rest = uu / LW;
        int ck   = rest & 1;
        int hp   = rest >> 1;
        int hh   = h0 + hp - 1;
        int ww   = w0 + wp - 1;
        s_ok[i] = (u < UNITS) && ((unsigned)hh < 128u) && ((unsigned)ww < 128u);
        int hc = hh < 0 ? 0 : (hh > 127 ? 127 : hh);   // clamped safe coords
        int wc = ww < 0 ? 0 : (ww > 127 ? 127 : ww);
        voff[i] = (unsigned)(ck * (8 * TD * HW) + hc * 128 + wc);
    }

    float rvH[2][8], rvC[2][8];      // two staged planes in flight

    auto issue = [&](int tt, float (&rv)[2][8]) {
        const int tc = ((unsigned)tt >= 31u) ? 0 : tt;
        const float* basep = xin + (size_t)tc * HW;
#pragma unroll
        for (int j = 0; j < 8; ++j) {
            const float* bj = basep + (size_t)j * (TD * HW);   // uniform
            rv[0][j] = bj[voff[0]];
            rv[1][j] = bj[voff[1]];
        }
    };

    // tz is wave-uniform: zero-write path is a uniform branch.
    auto lds_write = [&](int wu, float (&rv)[2][8], bool tz) {
        if (!tz) {
#pragma unroll
            for (int i = 0; i < 2; ++i) {
                if (s_ok[i]) {
                    union { short8 s; unsigned u[4]; } v;
#pragma unroll
                    for (int k = 0; k < 4; ++k)
                        v.u[k] = cvtpk(rv[i][2 * k], rv[i][2 * k + 1]);
                    ring[wu + tid + i * 256] = v.s;
                }
            }
        } else {
            short8 z = (short8)0;
#pragma unroll
            for (int i = 0; i < 2; ++i)
                if (s_ok[i]) ring[wu + tid + i * 256] = z;
        }
    };

    // ---- ring tap offsets, packed 2x16b into 7 regs (t-invariant) ----
    int roffp[7];
#pragma unroll
    for (int s2 = 0; s2 < 7; ++s2) {
        int r01[2];
#pragma unroll
        for (int e = 0; e < 2; ++e) {
            int s = 2 * s2 + e;
            int T = 2 * s + (q >> 1); if (T > 26) T = 26;
            int kd = T / 9, rr = T - kd * 9, kh = rr / 3, kw = rr - kh * 3;
            r01[e] = (((wv + kh) * 2 + (q & 1)) * LW + px + kw) * 16;  // bytes
        }
        roffp[s2] = (r01[0] & 0xffff) | (r01[1] << 16);
    }
    const int kd4 = q >> 1;          // kd for tap 8 (kd=0) / 9 (kd=1) at s=4

    // bias per lane: channel = g*16 + q*4 + r
    float4v bv[3];
#pragma unroll
    for (int g = 0; g < 3; ++g)
        bv[g] = (float4v){bias[g * 16 + q * 4 + 0], bias[g * 16 + q * 4 + 1],
                          bias[g * 16 + q * 4 + 2], bias[g * 16 + q * 4 + 3]};

    float* po = out + ((size_t)(n * 16 + q * 4) * TD) * HW
                    + (size_t)(h0 + wv) * 128 + w0 + px;
    float cst[2][4] = {{0.f,0.f,0.f,0.f},{0.f,0.f,0.f,0.f}};

    auto activate = [&](float4v (&acc)[2][3]) {     // one t: gates+pool+store
#pragma unroll
        for (int tile = 0; tile < 2; ++tile) {
#pragma unroll
            for (int r = 0; r < 4; ++r) {
                float az = acc[tile][0][r];
                float af = acc[tile][1][r];
                float ao = acc[tile][2][r];
                float z = 1.f - 2.f * frcp(__expf(2.f * az) + 1.f);
                float f = frcp(1.f + __expf(-af));
                float o = frcp(1.f + __expf(-ao));
                float c = f * cst[tile][r] + (1.f - f) * z;
                cst[tile][r] = c;
                po[(size_t)r * (TD * HW) + tile * 16] = o * c;
            }
        }
        po += HW;
    };

    // ---- prologue. slot(p) = p%4; plane -1 -> slot 3 (zeros).
    //      Zero-fill and plane-writes of one unit can come from different
    //      threads (slots not 256-aligned) -> barrier between them. ----
    BARRIER();
    issue(0, rvH); lds_write(0 * UNITS, rvH, false);
    issue(1, rvH); lds_write(1 * UNITS, rvH, false);
    issue(2, rvH); lds_write(2 * UNITS, rvH, false);
    issue(3, rvH);                   // consumed at mid of iter t=0
    issue(4, rvC);                   // consumed at mid of iter t=0
    BARRIER();

    // 2t body: slots r0..r3 hold planes t-1..t+2. MFMA for t reads r0..r2,
    // for t+1 reads r1..r3, sharing each weight-frag read. Mid-barrier, then
    // planes t+3,t+4 (staged last mid) overwrite r0,r1; issue t+5,t+6.
    int r0 = 3 * SLOTB, r1 = 0, r2 = SLOTB, r3 = 2 * SLOTB;
    for (int t = 0; t < 30; t += 2) {
        float4v accA[2][3], accB[2][3];
#pragma unroll
        for (int g = 0; g < 3; ++g) {
            accA[0][g] = bv[g]; accA[1][g] = bv[g];
            accB[0][g] = bv[g]; accB[1][g] = bv[g];
        }

        const int rr[4] = {r0, r1, r2, r3};
        constexpr int kdt[14] = {0,0,0,0, 0 /*s=4 special*/, 1,1,1,1, 2,2,2,2,2};
        const char* ringb = (const char*)ring;
#pragma unroll
        for (int s = 0; s < 14; ++s) {
            int ro  = (roffp[s >> 1] >> ((s & 1) * 16)) & 0xffff;
            int sbA = (s == 4) ? (kd4 ? r1 : r0) : rr[kdt[s]];       // time t
            int sbB = (s == 4) ? (kd4 ? r2 : r1) : rr[kdt[s] + 1];   // time t+1
            const short8* bpA = (const short8*)(ringb + sbA + ro);
            const short8* bpB = (const short8*)(ringb + sbB + ro);
            short8 wf0 = wlds[(s * 3 + 0) * 64 + lane];   // shared by t,t+1
            short8 wf1 = wlds[(s * 3 + 1) * 64 + lane];
            short8 wf2 = wlds[(s * 3 + 2) * 64 + lane];
            short8 a0 = bpA[0], a1 = bpA[16];
            accA[0][0] = MFMA(wf0, a0, accA[0][0]); accA[1][0] = MFMA(wf0, a1, accA[1][0]);
            accA[0][1] = MFMA(wf1, a0, accA[0][1]); accA[1][1] = MFMA(wf1, a1, accA[1][1]);
            accA[0][2] = MFMA(wf2, a0, accA[0][2]); accA[1][2] = MFMA(wf2, a1, accA[1][2]);
            short8 c0 = bpB[0], c1 = bpB[16];
            accB[0][0] = MFMA(wf0, c0, accB[0][0]); accB[1][0] = MFMA(wf0, c1, accB[1][0]);
            accB[0][1] = MFMA(wf1, c0, accB[0][1]); accB[1][1] = MFMA(wf1, c1, accB[1][1]);
            accB[0][2] = MFMA(wf2, c0, accB[0][2]); accB[1][2] = MFMA(wf2, c1, accB[1][2]);
        }
        BARRIER();                        // all reads of r0,r1 complete
        lds_write(r0 >> 4, rvH, (t + 3) >= 31);   // plane t+3 -> slot(t-1)
        lds_write(r1 >> 4, rvC, (t + 4) >= 31);   // plane t+4 -> slot(t)
        issue(t + 5, rvH);                // consumed at next mid
        issue(t + 6, rvC);
        activate(accA);                   // time t   (updates cst, stores)
        activate(accB);                   // time t+1
        BARRIER();                        // writes visible for next MFMA
        int ta = r0, tb = r1;             // rotate by 2
        r0 = r2; r1 = r3; r2 = ta; r3 = tb;
    }

    // ---- tail t=30: planes 29,30,31 in r0,r1,r2 (31 = zeros) ----
    {
        float4v acc[2][3];
#pragma unroll
        for (int g = 0; g < 3; ++g) { acc[0][g] = bv[g]; acc[1][g] = bv[g]; }
        const int rr[4] = {r0, r1, r2, r3};
        constexpr int kdt[14] = {0,0,0,0, 0, 1,1,1,1, 2,2,2,2,2};
        const char* ringb = (const char*)ring;
#pragma unroll
        for (int s = 0; s < 14; ++s) {
            int ro = (roffp[s >> 1] >> ((s & 1) * 16)) & 0xffff;
            int sb = (s == 4) ? (kd4 ? r1 : r0) : rr[kdt[s]];
            const short8* bp = (const short8*)(ringb + sb + ro);
            short8 wf0 = wlds[(s * 3 + 0) * 64 + lane];
            short8 wf1 = wlds[(s * 3 + 1) * 64 + lane];
            short8 wf2 = wlds[(s * 3 + 2) * 64 + lane];
            short8 b0 = bp[0], b1 = bp[16];
            acc[0][0] = MFMA(wf0, b0, acc[0][0]); acc[1][0] = MFMA(wf0, b1, acc[1][0]);
            acc[0][1] = MFMA(wf1, b0, acc[0][1]); acc[1][1] = MFMA(wf1, b1, acc[1][1]);
            acc[0][2] = MFMA(wf2, b0, acc[0][2]); acc[1][2] = MFMA(wf2, b1, acc[1][2]);
        }
        activate(acc);
    }
}

extern "C" void kernel_launch(void* const* d_in, const int* in_sizes, int n_in,
                              void* d_out, int out_size, void* d_ws, size_t ws_size,
                              hipStream_t stream) {
    const float* x    = (const float*)d_in[0];
    const float* wt   = (const float*)d_in[1];
    const float* bias = (const float*)d_in[2];
    float* out = (float*)d_out;

    static bool configured = false;
    if (!configured) {
        hipFuncSetAttribute((const void*)qrnn_mfma8,
                            hipFuncAttributeMaxDynamicSharedMemorySize,
                            SMEM_BYTES);
        configured = true;
    }

    // grid: n(4) x hblk(32) x wblk(4) = 512 blocks of 256 threads (4 waves)
    qrnn_mfma8<<<dim3(512), dim3(256), SMEM_BYTES, stream>>>(x, wt, bias, out);
}

// Round 9
// 289.427 us; speedup vs baseline: 1.1865x; 1.0383x over previous
//
#include <hip/hip_runtime.h>

// QRNN3D fused: conv3d(16->48,3x3x3,SAME) + gates + fo-pool via bf16 MFMA.
// Round 12: r6 (135us) structure + DEFERRED ACTIVATION (software pipeline).
// r11 taught us LDS BW is not binding (30% traffic cut -> 10% SLOWER). The
// r6 wall decomposes as LDS 43% / VALU 26% / MFMA 26% on separate pipes but
// phase-serialized per wave (MFMA block -> activation -> barrier), so pipes
// idle in turn. Fix: iteration t runs MFMA(t) -> acc_cur while executing
// activation(t-1) from acc_prev — register-complete, independent of t's
// ds_reads — in the SAME basic block, so the scheduler interleaves the
// ~48 transcendentals/thread into MFMA wait slots. Ping-pong accA/accB
// (compile-time roles), t=0 peeled, trailing activate after the loop.
// Everything else identical to r6: NSLOT=4 ring, one barrier per t,
// lds_write at top, full weights in LDS, dynamic 69120B smem.
//
// GEMM: gates[48][px] = W[48][K=448] * im2col[K][px]; K = tap*16+ic,
// tap = kd*9+kh*3+kw (27 real, pad tap 27 has W==0).
// mfma_f32_16x16x32_bf16: A[m][k=q*8+j] = W, B[k][n=px], C/D col=lane&15,
// row=q*4+reg. Wave owns 32 px x 16 hidden ch; z/f/o accs lane-aligned so
// the t-recurrence is per-lane register math.

typedef __attribute__((ext_vector_type(8))) short short8;
typedef __attribute__((ext_vector_type(4))) float float4v;

#define TD 31
#define HW (128 * 128)
#define LH 6                         // 4 tile rows + 2 halo
#define LW 34                        // 32 tile cols + 2 halo
#define UNITS (LH * 2 * LW)          // 408 short8 units per plane
#define NSLOT 4
#define SLOTB (UNITS * 16)           // 6528 B per ring slot
#define WUNITS (14 * 3 * 64)         // 2688 weight units (43008 B)
#define SMEM_BYTES ((WUNITS + NSLOT * UNITS) * 16)   // 69120

__device__ __forceinline__ short f2bf(float f) {
    unsigned u = __float_as_uint(f);
    u = (u + 0x7FFFu + ((u >> 16) & 1u)) >> 16;   // RNE
    return (short)u;
}

__device__ __forceinline__ float frcp(float x) { return __builtin_amdgcn_rcpf(x); }

__device__ __forceinline__ unsigned cvtpk(float lo, float hi) {
    unsigned r;
    asm("v_cvt_pk_bf16_f32 %0, %1, %2" : "=v"(r) : "v"(lo), "v"(hi));
    return r;
}

// Barrier WITHOUT the compiler's vmcnt(0) drain. lgkmcnt(0) orders LDS;
// global loads target private registers (compiler-tracked vmcnt at use).
#define BARRIER() asm volatile("s_waitcnt lgkmcnt(0)\n\ts_barrier" ::: "memory")

#define MFMA(A, B, C) __builtin_amdgcn_mfma_f32_16x16x32_bf16((A), (B), (C), 0, 0, 0)

__global__ __launch_bounds__(256, 2) void qrnn_mfma9(
    const float* __restrict__ x,     // (4,16,31,128,128)
    const float* __restrict__ wt,    // (48,16,27)
    const float* __restrict__ bias,  // (48)
    float* __restrict__ out)         // (4,16,31,128,128)
{
    extern __shared__ short8 smem[];
    short8* wlds = smem;             // [WUNITS]
    short8* ring = smem + WUNITS;    // [NSLOT*UNITS]

    const int tid  = threadIdx.x;
    const int lane = tid & 63;
    const int wv   = tid >> 6;       // wave id = h row in tile
    const int q    = lane >> 4;
    const int px   = lane & 15;
    const int b    = blockIdx.x;     // 512 blocks
    const int n    = b >> 7;
    const int h0   = ((b >> 2) & 31) * 4;
    const int w0   = (b & 3) * 32;

    const float* xin = x + (size_t)n * (16 * TD * HW);

    // ---- fill weight LDS once: wlds[(s*3+g)*64 + lane] = A-frag ----
    for (int k = 0; k < 11; ++k) {
        int u = tid + k * 256;
        if (u < WUNITS) {
            int l = u & 63, rest = u >> 6;
            int g = rest % 3, s = rest / 3;
            int qq = l >> 4, m = l & 15;
            short8 a;
#pragma unroll
            for (int j = 0; j < 8; ++j) {
                int kk = s * 32 + qq * 8 + j;
                int tap = kk >> 4, ic = kk & 15;
                float v = (tap < 27) ? wt[((size_t)((g * 16 + m) * 16 + ic)) * 27 + tap] : 0.f;
                a[j] = f2bf(v);
            }
            wlds[u] = a;
        }
    }
    // ---- zero all ring slots once (halo-invalid units stay 0 forever;
    //      plane -1 = slot 3 stays 0) ----
    {
        short8 z = (short8)0;
        for (int k = 0; k < 7; ++k) {
            int u = tid + k * 256;
            if (u < NSLOT * UNITS) ring[u] = z;
        }
    }

    // ---- staging: 1 VGPR voffset per unit + uniform SGPR plane bases ----
    unsigned voff[2];
    bool s_ok[2];
#pragma unroll
    for (int i = 0; i < 2; ++i) {
        int u    = tid + i * 256;
        int uu   = (u < UNITS) ? u : 0;
        int wp   = uu % LW;
        int rest = uu / LW;
        int ck   = rest & 1;
        int hp   = rest >> 1;
        int hh   = h0 + hp - 1;
        int ww   = w0 + wp - 1;
        s_ok[i] = (u < UNITS) && ((unsigned)hh < 128u) && ((unsigned)ww < 128u);
        int hc = hh < 0 ? 0 : (hh > 127 ? 127 : hh);   // clamped safe coords
        int wc = ww < 0 ? 0 : (ww > 127 ? 127 : ww);
        voff[i] = (unsigned)(ck * (8 * TD * HW) + hc * 128 + wc);
    }

    float rv[2][8];                  // single staging buffer

    auto issue = [&](int tt) {
        const int tc = ((unsigned)tt >= 31u) ? 0 : tt;
        const float* basep = xin + (size_t)tc * HW;
#pragma unroll
        for (int j = 0; j < 8; ++j) {
            const float* bj = basep + (size_t)j * (TD * HW);   // uniform
            rv[0][j] = bj[voff[0]];
            rv[1][j] = bj[voff[1]];
        }
    };

    // tz is wave-uniform: zero-write path is a uniform branch (t>=29 only).
    auto lds_write = [&](int wu, bool tz) {
        if (!tz) {
#pragma unroll
            for (int i = 0; i < 2; ++i) {
                if (s_ok[i]) {
                    union { short8 s; unsigned u[4]; } v;
#pragma unroll
                    for (int k = 0; k < 4; ++k)
                        v.u[k] = cvtpk(rv[i][2 * k], rv[i][2 * k + 1]);
                    ring[wu + tid + i * 256] = v.s;
                }
            }
        } else {
            short8 z = (short8)0;
#pragma unroll
            for (int i = 0; i < 2; ++i)
                if (s_ok[i]) ring[wu + tid + i * 256] = z;
        }
    };

    // ---- ring tap offsets (t-invariant). kd compile-time except s=4. ----
    int roff[14];
#pragma unroll
    for (int s = 0; s < 14; ++s) {
        int T = 2 * s + (q >> 1); if (T > 26) T = 26;
        int kd = T / 9, rr = T - kd * 9, kh = rr / 3, kw = rr - kh * 3;
        roff[s] = (((wv + kh) * 2 + (q & 1)) * LW + px + kw) * 16;  // bytes
    }
    const int kd4 = q >> 1;          // kd for s==4: taps 8 (kd=0) / 9 (kd=1)

    // bias per lane: channel = g*16 + q*4 + r
    float4v bv[3];
#pragma unroll
    for (int g = 0; g < 3; ++g)
        bv[g] = (float4v){bias[g * 16 + q * 4 + 0], bias[g * 16 + q * 4 + 1],
                          bias[g * 16 + q * 4 + 2], bias[g * 16 + q * 4 + 3]};

    float* po = out + ((size_t)(n * 16 + q * 4) * TD) * HW
                    + (size_t)(h0 + wv) * 128 + w0 + px;
    float cst[2][4] = {{0.f,0.f,0.f,0.f},{0.f,0.f,0.f,0.f}};

    float4v accA[2][3], accB[2][3];  // ping-pong: MFMA(t) || activate(t-1)

    int r0 = 3 * SLOTB, r1 = 0, r2 = SLOTB, r3 = 2 * SLOTB;

    auto do_mfma = [&](float4v (&acc)[2][3]) {
#pragma unroll
        for (int g = 0; g < 3; ++g) { acc[0][g] = bv[g]; acc[1][g] = bv[g]; }
        const int pk[3] = {r0, r1, r2};
        constexpr int kdt[14] = {0,0,0,0, 0 /*s=4 special*/, 1,1,1,1, 2,2,2,2,2};
        const char* ringb = (const char*)ring;
#pragma unroll
        for (int s = 0; s < 14; ++s) {
            int sb = (s == 4) ? (kd4 ? r1 : r0) : pk[kdt[s]];
            const short8* bp = (const short8*)(ringb + sb + roff[s]);
            short8 wf0 = wlds[(s * 3 + 0) * 64 + lane];
            short8 wf1 = wlds[(s * 3 + 1) * 64 + lane];
            short8 wf2 = wlds[(s * 3 + 2) * 64 + lane];
            short8 b0 = bp[0];           // ds_read_b128, conflict-free
            short8 b1 = bp[16];          // +16 w cols, offset:256 immediate
            acc[0][0] = MFMA(wf0, b0, acc[0][0]); acc[1][0] = MFMA(wf0, b1, acc[1][0]);
            acc[0][1] = MFMA(wf1, b0, acc[0][1]); acc[1][1] = MFMA(wf1, b1, acc[1][1]);
            acc[0][2] = MFMA(wf2, b0, acc[0][2]); acc[1][2] = MFMA(wf2, b1, acc[1][2]);
        }
    };

    auto activate = [&](float4v (&acc)[2][3]) {   // gates+fo-pool+store, 1 t
#pragma unroll
        for (int tile = 0; tile < 2; ++tile) {
#pragma unroll
            for (int r = 0; r < 4; ++r) {
                float az = acc[tile][0][r];
                float af = acc[tile][1][r];
                float ao = acc[tile][2][r];
                float z = 1.f - 2.f * frcp(__expf(2.f * az) + 1.f);
                float f = frcp(1.f + __expf(-af));
                float o = frcp(1.f + __expf(-ao));
                float c = f * cst[tile][r] + (1.f - f) * z;
                cst[tile][r] = c;
                po[(size_t)r * (TD * HW) + tile * 16] = o * c;
            }
        }
        po += HW;
    };

    auto rotate = [&]() { int tmp = r0; r0 = r1; r1 = r2; r2 = r3; r3 = tmp; };

    // ---- prologue. slot(p) = p&3; plane -1 -> slot 3 (zeros).
    //      Ring slots are 408 units (NOT 256-aligned): zero-fill and
    //      plane-write of one unit can come from different threads ->
    //      barrier between them is REQUIRED. ----
    BARRIER();
    issue(0); lds_write(0 * UNITS, false);
    issue(1); lds_write(1 * UNITS, false);
    issue(2);                        // rv = plane 2, written at t=0
    BARRIER();

    // ---- peeled t=0: no pending activation ----
    lds_write(r3 >> 4, false);       // plane 2 -> slot 2
    issue(3);
    do_mfma(accA);                   // acc(t=0)
    BARRIER();
    rotate();

    // ---- pipelined pairs: t = (1,2),(3,4),...,(29,30) ----
    // half(t): write plane t+2, issue t+3, MFMA(t)->accCur while the
    // scheduler interleaves activate(accPrev) [t-1, register-complete,
    // independent of this iteration's ds_reads] into the MFMA wait slots.
    for (int t = 1; t < 30; t += 2) {
        // half 1: odd t -> accB, retire accA (t-1)
        lds_write(r3 >> 4, t >= 29);
        issue(t + 3);
        do_mfma(accB);
        activate(accA);
        BARRIER();
        rotate();
        // half 2: even t+1 -> accA, retire accB (t)
        lds_write(r3 >> 4, (t + 1) >= 29);
        issue(t + 4);
        do_mfma(accA);
        activate(accB);
        BARRIER();
        rotate();
    }

    activate(accA);                  // retire t=30
}

extern "C" void kernel_launch(void* const* d_in, const int* in_sizes, int n_in,
                              void* d_out, int out_size, void* d_ws, size_t ws_size,
                              hipStream_t stream) {
    const float* x    = (const float*)d_in[0];
    const float* wt   = (const float*)d_in[1];
    const float* bias = (const float*)d_in[2];
    float* out = (float*)d_out;

    static bool configured = false;
    if (!configured) {
        hipFuncSetAttribute((const void*)qrnn_mfma9,
                            hipFuncAttributeMaxDynamicSharedMemorySize,
                            SMEM_BYTES);
        configured = true;
    }

    // grid: n(4) x hblk(32) x wblk(4) = 512 blocks of 256 threads (4 waves)
    qrnn_mfma9<<<dim3(512), dim3(256), SMEM_BYTES, stream>>>(x, wt, bias, out);
}